// Round 1
// baseline (685.962 us; speedup 1.0000x reference)
//
#include <hip/hip_runtime.h>
#include <math.h>

#define NEG_SLOPE 0.2f

typedef short s16x8 __attribute__((ext_vector_type(8)));
typedef float f32x16 __attribute__((ext_vector_type(16)));

// float -> bf16 (round-to-nearest-even), and back
__device__ __forceinline__ unsigned short f2bf(float x){
  unsigned int u = __float_as_uint(x);
  unsigned int r = u + 0x7FFFu + ((u >> 16) & 1u);
  return (unsigned short)(r >> 16);
}
__device__ __forceinline__ float bf2f(unsigned short h){
  return __uint_as_float(((unsigned int)h) << 16);
}

// ---------------------------------------------------------------- CSR build
__global__ void deg_count_kernel(const int* __restrict__ dst, int* __restrict__ deg, int E){
  int e = blockIdx.x * blockDim.x + threadIdx.x;
  if (e < E) atomicAdd(&deg[dst[e]], 1);
}

__global__ void base_assign_kernel(const int* __restrict__ deg, int* __restrict__ base,
                                   int* __restrict__ counter, int N){
  int n = blockIdx.x * blockDim.x + threadIdx.x;
  if (n < N) base[n] = atomicAdd(counter, deg[n]);
}

__global__ void fill_kernel(const int* __restrict__ ei, const float* __restrict__ ea,
                            const int* __restrict__ base, int* __restrict__ pos,
                            int2* __restrict__ csr_pack, int E){
  int e = blockIdx.x * blockDim.x + threadIdx.x;
  if (e >= E) return;
  int s = ei[e], d = ei[E + e];
  int p = atomicAdd(&pos[d], 1);
  csr_pack[base[d] + p] = make_int2(s, __float_as_int(ea[e]));
}

// ---------------------------------------------------------------- weight prep
// Pack W1|W2 (each [K][NOUT] fp32 row-major) into bf16 hi/lo arrays laid out as
// [kgroup][col(2*NOUT)][8 k-elems] -- exactly the MFMA B-fragment LDS order, so
// the GEMM stages B with a pure linear copy. Zero-pads k >= K.
__device__ __forceinline__ void pack_pair(const float* __restrict__ W1,
                                          const float* __restrict__ W2,
                                          short* __restrict__ H, short* __restrict__ L,
                                          int id, int K, int NOUT){
  int BN = 2 * NOUT;
  int kg = id / BN, cb = id - kg * BN;
  const float* W = (cb < NOUT) ? W1 : W2;
  int c = (cb < NOUT) ? cb : cb - NOUT;
  s16x8 hv, lv;
  #pragma unroll
  for (int e = 0; e < 8; e++){
    int k = kg * 8 + e;
    float v = (k < K) ? W[(long)k * NOUT + c] : 0.f;
    unsigned short h = f2bf(v);
    hv[e] = (short)h;
    lv[e] = (short)f2bf(v - bf2f(h));
  }
  *(s16x8*)&H[(long)id * 8] = hv;
  *(s16x8*)&L[(long)id * 8] = lv;
}

__global__ void prep_w_kernel(const float* Wl1, const float* Wr1, short* H1, short* L1,
                              const float* Wl2, const float* Wr2, short* H2, short* L2,
                              const float* Wl3, const float* Wr3, short* H3, short* L3,
                              const float* Wl4, const float* Wr4, short* H4, short* L4){
  int id = blockIdx.x * blockDim.x + threadIdx.x;
  if (id < 512)  { pack_pair(Wl1, Wr1, H1, L1, id, 15, 128); return; }   // KG=2,  BN=256
  id -= 512;
  if (id < 4096) { pack_pair(Wl2, Wr2, H2, L2, id, 128, 128); return; }  // KG=16, BN=256
  id -= 4096;
  if (id < 4096) { pack_pair(Wl3, Wr3, H3, L3, id, 128, 128); return; }
  id -= 4096;
  if (id < 2048) { pack_pair(Wl4, Wr4, H4, L4, id, 128, 64); return; }   // KG=16, BN=128
}

// ---------------------------------------------------------------- MFMA dual GEMM
// Y1 = X@W1 + b1, Y2 = X@W2 + b2 via split-bf16 3-product emulation:
//   X = Xh + Xl, W = Wh + Wl (bf16 each); Y ~= Xh*Wh + Xh*Wl + Xl*Wh (fp32 acc).
// Dropped Xl*Wl term ~2^-18 relative. Block: 64 rows x BN cols, 4 waves (2M x 2N),
// each wave one 32x32 MFMA tile x NR col-frags. K chunked 16 at a time.
// Fragment layouts (gfx950 v_mfma_f32_32x32x16_bf16):
//   A: row = lane&31, k = 8*(lane>>5)+e     B: col = lane&31, k = 8*(lane>>5)+e
//   D: col = lane&31, row = (reg&3) + 8*(reg>>2) + 4*(lane>>5)
template<int NOUT, int K>
__global__ __launch_bounds__(256, 2) void gemm_dual_mfma(
    const float* __restrict__ X,
    const short* __restrict__ BH, const short* __restrict__ BL,
    const float* __restrict__ b1, const float* __restrict__ b2,
    float* __restrict__ Y1, float* __restrict__ Y2, int N)
{
  constexpr int BM     = 64;
  constexpr int BN     = 2 * NOUT;
  constexpr int KSTEPS = (K + 15) / 16;     // one 32x32x16 MFMA step each
  constexpr int KG     = 2 * KSTEPS;        // k-groups of 8 in A staging
  constexpr int NR     = NOUT / 32;         // col fragments per wave
  constexpr int AST    = BM + 1;            // padded A row-stride (16B units) -> no write conflicts

  __shared__ s16x8 Ah_s[KG * AST];
  __shared__ s16x8 Al_s[KG * AST];
  __shared__ s16x8 Bh_s[2 * BN];
  __shared__ s16x8 Bl_s[2 * BN];

  int tid   = threadIdx.x;
  int lane  = tid & 63;
  int wid   = tid >> 6;
  int wm    = wid >> 1, wn = wid & 1;
  int llane = lane & 31, hlane = lane >> 5;
  int r0    = blockIdx.x * BM;

  // ---- stage A (full K) with fp32 -> bf16 hi/lo conversion
  for (int idx = tid; idx < BM * KG; idx += 256){
    int kg = idx % KG, r = idx / KG;
    int row = r0 + r;
    float v[8];
    if constexpr (K % 8 == 0){
      float4 p0 = {0.f,0.f,0.f,0.f}, p1 = {0.f,0.f,0.f,0.f};
      if (row < N){
        p0 = *(const float4*)(X + (long)row * K + kg * 8);
        p1 = *(const float4*)(X + (long)row * K + kg * 8 + 4);
      }
      v[0]=p0.x; v[1]=p0.y; v[2]=p0.z; v[3]=p0.w;
      v[4]=p1.x; v[5]=p1.y; v[6]=p1.z; v[7]=p1.w;
    } else {
      #pragma unroll
      for (int e = 0; e < 8; e++){
        int k = kg * 8 + e;
        v[e] = (row < N && k < K) ? X[(long)row * K + k] : 0.f;
      }
    }
    s16x8 hv, lv;
    #pragma unroll
    for (int e = 0; e < 8; e++){
      unsigned short h = f2bf(v[e]);
      hv[e] = (short)h;
      lv[e] = (short)f2bf(v[e] - bf2f(h));
    }
    Ah_s[kg * AST + r] = hv;
    Al_s[kg * AST + r] = lv;
  }

  f32x16 acc[NR];
  #pragma unroll
  for (int n = 0; n < NR; n++)
    #pragma unroll
    for (int i = 0; i < 16; i++) acc[n][i] = 0.f;

  for (int ks = 0; ks < KSTEPS; ++ks){
    // stage B chunk (pure linear copy of prepacked bf16)
    const s16x8* sh = (const s16x8*)BH + (long)(2 * BN) * ks;
    const s16x8* sl = (const s16x8*)BL + (long)(2 * BN) * ks;
    for (int i = tid; i < 2 * BN; i += 256){
      Bh_s[i] = sh[i];
      Bl_s[i] = sl[i];
    }
    __syncthreads();
    int aoff = (2 * ks + hlane) * AST + wm * 32 + llane;
    s16x8 ah = Ah_s[aoff];
    s16x8 al = Al_s[aoff];
    #pragma unroll
    for (int n = 0; n < NR; n++){
      int boff = hlane * BN + wn * NOUT + n * 32 + llane;
      s16x8 bh = Bh_s[boff];
      s16x8 bl = Bl_s[boff];
      acc[n] = __builtin_amdgcn_mfma_f32_32x32x16_bf16(ah, bh, acc[n], 0, 0, 0);
      acc[n] = __builtin_amdgcn_mfma_f32_32x32x16_bf16(ah, bl, acc[n], 0, 0, 0);
      acc[n] = __builtin_amdgcn_mfma_f32_32x32x16_bf16(al, bh, acc[n], 0, 0, 0);
    }
    if (ks + 1 < KSTEPS) __syncthreads();
  }

  // ---- epilogue: bias + store (wave n=0 -> Y1, n=1 -> Y2)
  const float* bsrc = wn ? b2 : b1;
  float* Y = wn ? Y2 : Y1;
  #pragma unroll
  for (int n = 0; n < NR; n++){
    float bias = bsrc[n * 32 + llane];
    #pragma unroll
    for (int reg = 0; reg < 16; reg++){
      int row = r0 + wm * 32 + (reg & 3) + 8 * (reg >> 2) + 4 * hlane;
      if (row < N)
        Y[(long)row * NOUT + n * 32 + llane] = acc[n][reg] + bias;
    }
  }
}

// ---------------------------------------------------------------- fused edge softmax + aggregation
// One wave per dst node (grid-stride). Lane = (edge-slot, head, channel-quad).
// No-max softmax; optional fused final linear. NEW: nt early-skip of fully-dead
// t-groups (wave-uniform) to avoid dummy-slot VALU work on degree tails.
template<int C>
__global__ __launch_bounds__(512) void agg_kernel(
    const float* __restrict__ xl, const float* __restrict__ xr,
    const int* __restrict__ base, const int* __restrict__ deg,
    const int2* __restrict__ csr_pack,
    const float* __restrict__ We, const float* __restrict__ att,
    const float* __restrict__ bias, float* __restrict__ hout,
    const float* __restrict__ Wlin, const float* __restrict__ blin,
    float* __restrict__ outF, int N, int do_elu)
{
  constexpr int HC  = 8 * C;
  constexpr int LPH = C / 4;       // lanes per head
  constexpr int LPE = 8 * LPH;     // lanes per edge (32 or 16)
  constexpr int ES  = 64 / LPE;    // edge slots per pass (2 or 4)
  constexpr int NP  = 4;           // passes per iteration
  constexpr int B   = ES * NP;     // edges per iteration (8 or 16)

  int lane = threadIdx.x & 63;
  int wv   = blockIdx.x * (blockDim.x >> 6) + (threadIdx.x >> 6);
  int nwv  = gridDim.x * (blockDim.x >> 6);
  int slot = lane / LPE;           // edge slot within pass
  int hl   = lane % LPE;           // position within edge
  int coff = hl * 4;               // channel offset: h*C + g*4 == hl*4

  float4 attv = *(const float4*)(att  + coff);
  float4 wev  = *(const float4*)(We   + coff);
  float4 bv   = *(const float4*)(bias + coff);
  float4 wl   = outF ? *(const float4*)(Wlin + coff) : make_float4(0.f,0.f,0.f,0.f);

  for (int n = wv; n < N; n += nwv){
    float4 xrv = *(const float4*)(xr + (long)n * HC + coff);
    float4 acc = {0.f, 0.f, 0.f, 0.f};
    float lrun = 0.f;
    int s0 = base[n], end = s0 + deg[n];

    for (int s = s0; s < end; s += B){
      int rem = end - s;
      int nt = (rem + ES - 1) / ES; if (nt > NP) nt = NP;   // wave-uniform
      int2 pk[NP]; bool val[NP];
      #pragma unroll
      for (int t = 0; t < NP; t++){
        if (t < nt){
          int idx = s + t * ES + slot;
          val[t] = idx < end;
          pk[t]  = csr_pack[val[t] ? idx : s0];
        }
      }
      float4 row[NP];
      #pragma unroll
      for (int t = 0; t < NP; t++){
        if (t < nt)
          row[t] = *(const float4*)(xl + (long)pk[t].x * HC + coff);
      }
      #pragma unroll
      for (int t = 0; t < NP; t++){
        if (t < nt){
          float eav = __int_as_float(pk[t].y);
          float t0 = row[t].x + xrv.x + eav * wev.x;
          float t1 = row[t].y + xrv.y + eav * wev.y;
          float t2 = row[t].z + xrv.z + eav * wev.z;
          float t3 = row[t].w + xrv.w + eav * wev.w;
          float m0 = fmaxf(t0, 0.f) + NEG_SLOPE * fminf(t0, 0.f);
          float m1 = fmaxf(t1, 0.f) + NEG_SLOPE * fminf(t1, 0.f);
          float m2 = fmaxf(t2, 0.f) + NEG_SLOPE * fminf(t2, 0.f);
          float m3 = fmaxf(t3, 0.f) + NEG_SLOPE * fminf(t3, 0.f);
          float p = ((m0 * attv.x + m1 * attv.y) + (m2 * attv.z + m3 * attv.w));
          #pragma unroll
          for (int o = 1; o < LPH; o <<= 1) p += __shfl_xor(p, o);
          float pe = val[t] ? __expf(p) : 0.f;
          lrun  += pe;
          acc.x += pe * row[t].x;
          acc.y += pe * row[t].y;
          acc.z += pe * row[t].z;
          acc.w += pe * row[t].w;
        }
      }
    }
    // reduce over edge slots
    #pragma unroll
    for (int o = LPE; o < 64; o <<= 1){
      lrun  += __shfl_xor(lrun, o);
      acc.x += __shfl_xor(acc.x, o);
      acc.y += __shfl_xor(acc.y, o);
      acc.z += __shfl_xor(acc.z, o);
      acc.w += __shfl_xor(acc.w, o);
    }
    float inv = 1.f / (lrun + 1e-16f);
    float4 o4;
    o4.x = acc.x * inv + bv.x;
    o4.y = acc.y * inv + bv.y;
    o4.z = acc.z * inv + bv.z;
    o4.w = acc.w * inv + bv.w;
    if (do_elu){
      o4.x = o4.x > 0.f ? o4.x : (__expf(o4.x) - 1.f);
      o4.y = o4.y > 0.f ? o4.y : (__expf(o4.y) - 1.f);
      o4.z = o4.z > 0.f ? o4.z : (__expf(o4.z) - 1.f);
      o4.w = o4.w > 0.f ? o4.w : (__expf(o4.w) - 1.f);
    }
    if (outF){
      float v = ((o4.x * wl.x + o4.y * wl.y) + (o4.z * wl.z + o4.w * wl.w));
      #pragma unroll
      for (int o = 1; o < LPE; o <<= 1) v += __shfl_xor(v, o);
      if (lane == 0) outF[n] = v + blin[0];
    } else {
      if (slot == 0)
        *(float4*)(hout + (long)n * HC + coff) = o4;
    }
  }
}

// ----------------------------------------------------------------
extern "C" void kernel_launch(void* const* d_in, const int* in_sizes, int n_in,
                              void* d_out, int out_size, void* d_ws, size_t ws_size,
                              hipStream_t stream)
{
  const float* x  = (const float*)d_in[0];
  const float* ea = (const float*)d_in[1];
  const int*   ei = (const int*)d_in[2];
  const int N = in_sizes[0] / 15;
  const int E = in_sizes[1];

  const float* P[28];
  for (int i = 0; i < 28; i++) P[i] = (const float*)d_in[3 + i];
  const float* Wlin = (const float*)d_in[31];
  const float* blin = (const float*)d_in[32];

  size_t off = 0;
  auto carve = [&](size_t bytes) -> char* {
    char* p = (char*)d_ws + off;
    off = (off + bytes + 255) & ~(size_t)255;
    return p;
  };
  int*   meta     = (int*)  carve(sizeof(int)  * (size_t)(3 * N + 64));
  int*   deg      = meta;                // [N] zeroed
  int*   pos      = meta + N;            // [N] zeroed
  int*   base     = meta + 2 * N;        // [N]
  int*   counter  = meta + 3 * N;        // [1] zeroed
  int2*  csr_pack = (int2*) carve(sizeof(int2) * (size_t)E);
  float* xl       = (float*)carve(sizeof(float) * (size_t)N * 128);
  float* xr       = (float*)carve(sizeof(float) * (size_t)N * 128);
  float* hA       = (float*)carve(sizeof(float) * (size_t)N * 128);
  float* hB       = (float*)carve(sizeof(float) * (size_t)N * 128);
  // prepacked bf16 hi/lo weights, MFMA B-fragment order
  short* ph1 = (short*)carve(sizeof(short) * 4096);
  short* pl1 = (short*)carve(sizeof(short) * 4096);
  short* ph2 = (short*)carve(sizeof(short) * 32768);
  short* pl2 = (short*)carve(sizeof(short) * 32768);
  short* ph3 = (short*)carve(sizeof(short) * 32768);
  short* pl3 = (short*)carve(sizeof(short) * 32768);
  short* ph4 = (short*)carve(sizeof(short) * 16384);
  short* pl4 = (short*)carve(sizeof(short) * 16384);

  hipMemsetAsync(deg,     0, sizeof(int) * (size_t)(2 * N), stream);
  hipMemsetAsync(counter, 0, sizeof(int), stream);

  int eb = (E + 255) / 256;
  int nb = (N + 255) / 256;
  deg_count_kernel  <<<eb, 256, 0, stream>>>(ei + E, deg, E);
  base_assign_kernel<<<nb, 256, 0, stream>>>(deg, base, counter, N);
  fill_kernel       <<<eb, 256, 0, stream>>>(ei, ea, base, pos, csr_pack, E);
  prep_w_kernel     <<<42, 256, 0, stream>>>(P[0],  P[2],  ph1, pl1,
                                             P[7],  P[9],  ph2, pl2,
                                             P[14], P[16], ph3, pl3,
                                             P[21], P[23], ph4, pl4);

  int gm    = (N + 63) / 64;  // 64-row MFMA tiles
  int agrid = 2048;           // agg: grid-stride, 8 waves/block

  // layer 1: din=15, H*C=128, ELU
  gemm_dual_mfma<128, 15><<<gm, 256, 0, stream>>>(x, ph1, pl1, P[1], P[3], xl, xr, N);
  agg_kernel<16><<<agrid, 512, 0, stream>>>(xl, xr, base, deg, csr_pack, P[4], P[5], P[6], hA,
                                            nullptr, nullptr, nullptr, N, 1);
  // layer 2: din=128, ELU
  gemm_dual_mfma<128, 128><<<gm, 256, 0, stream>>>(hA, ph2, pl2, P[8], P[10], xl, xr, N);
  agg_kernel<16><<<agrid, 512, 0, stream>>>(xl, xr, base, deg, csr_pack, P[11], P[12], P[13], hB,
                                            nullptr, nullptr, nullptr, N, 1);
  // layer 3: din=128, ELU
  gemm_dual_mfma<128, 128><<<gm, 256, 0, stream>>>(hB, ph3, pl3, P[15], P[17], xl, xr, N);
  agg_kernel<16><<<agrid, 512, 0, stream>>>(xl, xr, base, deg, csr_pack, P[18], P[19], P[20], hA,
                                            nullptr, nullptr, nullptr, N, 1);
  // layer 4: din=128, H*C=64, no ELU + fused final linear 64->1
  gemm_dual_mfma<64, 128><<<gm, 256, 0, stream>>>(hA, ph4, pl4, P[22], P[24], xl, xr, N);
  agg_kernel<8><<<agrid, 512, 0, stream>>>(xl, xr, base, deg, csr_pack, P[25], P[26], P[27], hB,
                                           Wlin, blin, (float*)d_out, N, 0);
}

// Round 2
// 576.836 us; speedup vs baseline: 1.1892x; 1.1892x over previous
//
#include <hip/hip_runtime.h>
#include <math.h>

#define NEG_SLOPE 0.2f

typedef short s16x8 __attribute__((ext_vector_type(8)));
typedef float f32x16 __attribute__((ext_vector_type(16)));

// float -> bf16 (round-to-nearest-even), and back
__device__ __forceinline__ unsigned short f2bf(float x){
  unsigned int u = __float_as_uint(x);
  unsigned int r = u + 0x7FFFu + ((u >> 16) & 1u);
  return (unsigned short)(r >> 16);
}
__device__ __forceinline__ float bf2f(unsigned short h){
  return __uint_as_float(((unsigned int)h) << 16);
}

// ---------------------------------------------------------------- CSR build
__global__ void deg_count_kernel(const int* __restrict__ dst, int* __restrict__ deg, int E){
  int e = blockIdx.x * blockDim.x + threadIdx.x;
  if (e < E) atomicAdd(&deg[dst[e]], 1);
}

__global__ void base_assign_kernel(const int* __restrict__ deg, int* __restrict__ base,
                                   int* __restrict__ counter, int N){
  int n = blockIdx.x * blockDim.x + threadIdx.x;
  if (n < N) base[n] = atomicAdd(counter, deg[n]);
}

__global__ void fill_kernel(const int* __restrict__ ei, const float* __restrict__ ea,
                            const int* __restrict__ base, int* __restrict__ pos,
                            int2* __restrict__ csr_pack, int E){
  int e = blockIdx.x * blockDim.x + threadIdx.x;
  if (e >= E) return;
  int s = ei[e], d = ei[E + e];
  int p = atomicAdd(&pos[d], 1);
  csr_pack[base[d] + p] = make_int2(s, __float_as_int(ea[e]));
}

// ---------------------------------------------------------------- weight prep
// Pack W1|W2 (each [K][NOUT] fp32 row-major) into bf16 hi/lo arrays laid out as
// [kgroup][col(2*NOUT)][8 k-elems] -- exactly the MFMA B-fragment LDS order, so
// the GEMM stages B with a pure linear copy. Zero-pads k >= K.
__device__ __forceinline__ void pack_pair(const float* __restrict__ W1,
                                          const float* __restrict__ W2,
                                          short* __restrict__ H, short* __restrict__ L,
                                          int id, int K, int NOUT){
  int BN = 2 * NOUT;
  int kg = id / BN, cb = id - kg * BN;
  const float* W = (cb < NOUT) ? W1 : W2;
  int c = (cb < NOUT) ? cb : cb - NOUT;
  s16x8 hv, lv;
  #pragma unroll
  for (int e = 0; e < 8; e++){
    int k = kg * 8 + e;
    float v = (k < K) ? W[(long)k * NOUT + c] : 0.f;
    unsigned short h = f2bf(v);
    hv[e] = (short)h;
    lv[e] = (short)f2bf(v - bf2f(h));
  }
  *(s16x8*)&H[(long)id * 8] = hv;
  *(s16x8*)&L[(long)id * 8] = lv;
}

__global__ void prep_w_kernel(const float* Wl1, const float* Wr1, short* H1, short* L1,
                              const float* Wl2, const float* Wr2, short* H2, short* L2,
                              const float* Wl3, const float* Wr3, short* H3, short* L3,
                              const float* Wl4, const float* Wr4, short* H4, short* L4){
  int id = blockIdx.x * blockDim.x + threadIdx.x;
  if (id < 512)  { pack_pair(Wl1, Wr1, H1, L1, id, 15, 128); return; }   // KG=2,  BN=256
  id -= 512;
  if (id < 4096) { pack_pair(Wl2, Wr2, H2, L2, id, 128, 128); return; }  // KG=16, BN=256
  id -= 4096;
  if (id < 4096) { pack_pair(Wl3, Wr3, H3, L3, id, 128, 128); return; }
  id -= 4096;
  if (id < 2048) { pack_pair(Wl4, Wr4, H4, L4, id, 128, 64); return; }   // KG=16, BN=128
}

// ---------------------------------------------------------------- MFMA dual GEMM
// Y1 = X@W1 + b1, Y2 = X@W2 + b2 via split-bf16 3-product emulation:
//   X = Xh + Xl, W = Wh + Wl (bf16 each); Y ~= Xh*Wh + Xh*Wl + Xl*Wh (fp32 acc).
// Dropped Xl*Wl term ~2^-18 relative. Block: 64 rows x BN cols, 4 waves (2M x 2N),
// each wave one 32x32 MFMA tile x NR col-frags. K chunked 16 at a time.
// Fragment layouts (gfx950 v_mfma_f32_32x32x16_bf16):
//   A: row = lane&31, k = 8*(lane>>5)+e     B: col = lane&31, k = 8*(lane>>5)+e
//   D: col = lane&31, row = (reg&3) + 8*(reg>>2) + 4*(lane>>5)
template<int NOUT, int K>
__global__ __launch_bounds__(256, 2) void gemm_dual_mfma(
    const float* __restrict__ X,
    const short* __restrict__ BH, const short* __restrict__ BL,
    const float* __restrict__ b1, const float* __restrict__ b2,
    float* __restrict__ Y1, float* __restrict__ Y2, int N)
{
  constexpr int BM     = 64;
  constexpr int BN     = 2 * NOUT;
  constexpr int KSTEPS = (K + 15) / 16;     // one 32x32x16 MFMA step each
  constexpr int KG     = 2 * KSTEPS;        // k-groups of 8 in A staging
  constexpr int NR     = NOUT / 32;         // col fragments per wave
  constexpr int AST    = BM + 1;            // padded A row-stride (16B units) -> no write conflicts

  __shared__ s16x8 Ah_s[KG * AST];
  __shared__ s16x8 Al_s[KG * AST];
  __shared__ s16x8 Bh_s[2 * BN];
  __shared__ s16x8 Bl_s[2 * BN];

  int tid   = threadIdx.x;
  int lane  = tid & 63;
  int wid   = tid >> 6;
  int wm    = wid >> 1, wn = wid & 1;
  int llane = lane & 31, hlane = lane >> 5;
  int r0    = blockIdx.x * BM;

  // ---- stage A (full K) with fp32 -> bf16 hi/lo conversion
  for (int idx = tid; idx < BM * KG; idx += 256){
    int kg = idx % KG, r = idx / KG;
    int row = r0 + r;
    float v[8];
    if constexpr (K % 8 == 0){
      float4 p0 = {0.f,0.f,0.f,0.f}, p1 = {0.f,0.f,0.f,0.f};
      if (row < N){
        p0 = *(const float4*)(X + (long)row * K + kg * 8);
        p1 = *(const float4*)(X + (long)row * K + kg * 8 + 4);
      }
      v[0]=p0.x; v[1]=p0.y; v[2]=p0.z; v[3]=p0.w;
      v[4]=p1.x; v[5]=p1.y; v[6]=p1.z; v[7]=p1.w;
    } else {
      #pragma unroll
      for (int e = 0; e < 8; e++){
        int k = kg * 8 + e;
        v[e] = (row < N && k < K) ? X[(long)row * K + k] : 0.f;
      }
    }
    s16x8 hv, lv;
    #pragma unroll
    for (int e = 0; e < 8; e++){
      unsigned short h = f2bf(v[e]);
      hv[e] = (short)h;
      lv[e] = (short)f2bf(v[e] - bf2f(h));
    }
    Ah_s[kg * AST + r] = hv;
    Al_s[kg * AST + r] = lv;
  }

  f32x16 acc[NR];
  #pragma unroll
  for (int n = 0; n < NR; n++)
    #pragma unroll
    for (int i = 0; i < 16; i++) acc[n][i] = 0.f;

  for (int ks = 0; ks < KSTEPS; ++ks){
    // stage B chunk (pure linear copy of prepacked bf16)
    const s16x8* sh = (const s16x8*)BH + (long)(2 * BN) * ks;
    const s16x8* sl = (const s16x8*)BL + (long)(2 * BN) * ks;
    for (int i = tid; i < 2 * BN; i += 256){
      Bh_s[i] = sh[i];
      Bl_s[i] = sl[i];
    }
    __syncthreads();
    int aoff = (2 * ks + hlane) * AST + wm * 32 + llane;
    s16x8 ah = Ah_s[aoff];
    s16x8 al = Al_s[aoff];
    #pragma unroll
    for (int n = 0; n < NR; n++){
      int boff = hlane * BN + wn * NOUT + n * 32 + llane;
      s16x8 bh = Bh_s[boff];
      s16x8 bl = Bl_s[boff];
      acc[n] = __builtin_amdgcn_mfma_f32_32x32x16_bf16(ah, bh, acc[n], 0, 0, 0);
      acc[n] = __builtin_amdgcn_mfma_f32_32x32x16_bf16(ah, bl, acc[n], 0, 0, 0);
      acc[n] = __builtin_amdgcn_mfma_f32_32x32x16_bf16(al, bh, acc[n], 0, 0, 0);
    }
    if (ks + 1 < KSTEPS) __syncthreads();
  }

  // ---- epilogue: bias + store (wave n=0 -> Y1, n=1 -> Y2)
  const float* bsrc = wn ? b2 : b1;
  float* Y = wn ? Y2 : Y1;
  #pragma unroll
  for (int n = 0; n < NR; n++){
    float bias = bsrc[n * 32 + llane];
    #pragma unroll
    for (int reg = 0; reg < 16; reg++){
      int row = r0 + wm * 32 + (reg & 3) + 8 * (reg >> 2) + 4 * hlane;
      if (row < N)
        Y[(long)row * NOUT + n * 32 + llane] = acc[n][reg] + bias;
    }
  }
}

// ---------------------------------------------------------------- fused edge softmax + aggregation
// One wave per dst node (grid-stride). Lane = (edge-slot, head, channel-quad):
// LPE = lanes per edge (32 for C=16, 16 for C=8) -> each row read is fully
// contiguous (512/256 B) b128 per lane. No-max softmax (logits O(1); exp is
// algebraically identical to ref's max-subtracted form) -> no cross-batch
// serial dependency, loads prefetch ahead. Optional fused final linear.
// NOTE (R1 post-mortem): do NOT predicate the NP loads on tail occupancy --
// wrapping them in `if (t < nt)` broke the 8-deep load batching and cost +50%
// (VALUBusy 53->32, BW 3.1->2.1 TB/s). Unconditional dummy loads are cheaper.
template<int C>
__global__ __launch_bounds__(512) void agg_kernel(
    const float* __restrict__ xl, const float* __restrict__ xr,
    const int* __restrict__ base, const int* __restrict__ deg,
    const int2* __restrict__ csr_pack,
    const float* __restrict__ We, const float* __restrict__ att,
    const float* __restrict__ bias, float* __restrict__ hout,
    const float* __restrict__ Wlin, const float* __restrict__ blin,
    float* __restrict__ outF, int N, int do_elu)
{
  constexpr int HC  = 8 * C;
  constexpr int LPH = C / 4;       // lanes per head
  constexpr int LPE = 8 * LPH;     // lanes per edge (32 or 16)
  constexpr int ES  = 64 / LPE;    // edge slots per pass (2 or 4)
  constexpr int NP  = 4;           // passes per iteration
  constexpr int B   = ES * NP;     // edges per iteration (8 or 16)

  int lane = threadIdx.x & 63;
  int wv   = blockIdx.x * (blockDim.x >> 6) + (threadIdx.x >> 6);
  int nwv  = gridDim.x * (blockDim.x >> 6);
  int slot = lane / LPE;           // edge slot within pass
  int hl   = lane % LPE;           // position within edge
  int coff = hl * 4;               // channel offset: h*C + g*4 == hl*4

  float4 attv = *(const float4*)(att  + coff);
  float4 wev  = *(const float4*)(We   + coff);
  float4 bv   = *(const float4*)(bias + coff);
  float4 wl   = outF ? *(const float4*)(Wlin + coff) : make_float4(0.f,0.f,0.f,0.f);

  for (int n = wv; n < N; n += nwv){
    float4 xrv = *(const float4*)(xr + (long)n * HC + coff);
    float4 acc = {0.f, 0.f, 0.f, 0.f};
    float lrun = 0.f;
    int s0 = base[n], end = s0 + deg[n];

    for (int s = s0; s < end; s += B){
      int2 pk[NP]; bool val[NP];
      #pragma unroll
      for (int t = 0; t < NP; t++){
        int idx = s + t * ES + slot;
        val[t] = idx < end;
        pk[t]  = csr_pack[val[t] ? idx : s0];
      }
      float4 row[NP];
      #pragma unroll
      for (int t = 0; t < NP; t++)
        row[t] = *(const float4*)(xl + (long)pk[t].x * HC + coff);
      #pragma unroll
      for (int t = 0; t < NP; t++){
        float eav = __int_as_float(pk[t].y);
        float t0 = row[t].x + xrv.x + eav * wev.x;
        float t1 = row[t].y + xrv.y + eav * wev.y;
        float t2 = row[t].z + xrv.z + eav * wev.z;
        float t3 = row[t].w + xrv.w + eav * wev.w;
        float m0 = fmaxf(t0, 0.f) + NEG_SLOPE * fminf(t0, 0.f);
        float m1 = fmaxf(t1, 0.f) + NEG_SLOPE * fminf(t1, 0.f);
        float m2 = fmaxf(t2, 0.f) + NEG_SLOPE * fminf(t2, 0.f);
        float m3 = fmaxf(t3, 0.f) + NEG_SLOPE * fminf(t3, 0.f);
        float p = ((m0 * attv.x + m1 * attv.y) + (m2 * attv.z + m3 * attv.w));
        #pragma unroll
        for (int o = 1; o < LPH; o <<= 1) p += __shfl_xor(p, o);
        float pe = val[t] ? __expf(p) : 0.f;
        lrun  += pe;
        acc.x += pe * row[t].x;
        acc.y += pe * row[t].y;
        acc.z += pe * row[t].z;
        acc.w += pe * row[t].w;
      }
    }
    // reduce over edge slots
    #pragma unroll
    for (int o = LPE; o < 64; o <<= 1){
      lrun  += __shfl_xor(lrun, o);
      acc.x += __shfl_xor(acc.x, o);
      acc.y += __shfl_xor(acc.y, o);
      acc.z += __shfl_xor(acc.z, o);
      acc.w += __shfl_xor(acc.w, o);
    }
    float inv = 1.f / (lrun + 1e-16f);
    float4 o4;
    o4.x = acc.x * inv + bv.x;
    o4.y = acc.y * inv + bv.y;
    o4.z = acc.z * inv + bv.z;
    o4.w = acc.w * inv + bv.w;
    if (do_elu){
      o4.x = o4.x > 0.f ? o4.x : (__expf(o4.x) - 1.f);
      o4.y = o4.y > 0.f ? o4.y : (__expf(o4.y) - 1.f);
      o4.z = o4.z > 0.f ? o4.z : (__expf(o4.z) - 1.f);
      o4.w = o4.w > 0.f ? o4.w : (__expf(o4.w) - 1.f);
    }
    if (outF){
      // fused final linear: out[n] = sum_c o_c * Wlin_c + blin
      float v = ((o4.x * wl.x + o4.y * wl.y) + (o4.z * wl.z + o4.w * wl.w));
      #pragma unroll
      for (int o = 1; o < LPE; o <<= 1) v += __shfl_xor(v, o);
      if (lane == 0) outF[n] = v + blin[0];
    } else {
      if (slot == 0)
        *(float4*)(hout + (long)n * HC + coff) = o4;
    }
  }
}

// ----------------------------------------------------------------
extern "C" void kernel_launch(void* const* d_in, const int* in_sizes, int n_in,
                              void* d_out, int out_size, void* d_ws, size_t ws_size,
                              hipStream_t stream)
{
  const float* x  = (const float*)d_in[0];
  const float* ea = (const float*)d_in[1];
  const int*   ei = (const int*)d_in[2];
  const int N = in_sizes[0] / 15;
  const int E = in_sizes[1];

  const float* P[28];
  for (int i = 0; i < 28; i++) P[i] = (const float*)d_in[3 + i];
  const float* Wlin = (const float*)d_in[31];
  const float* blin = (const float*)d_in[32];

  size_t off = 0;
  auto carve = [&](size_t bytes) -> char* {
    char* p = (char*)d_ws + off;
    off = (off + bytes + 255) & ~(size_t)255;
    return p;
  };
  int*   meta     = (int*)  carve(sizeof(int)  * (size_t)(3 * N + 64));
  int*   deg      = meta;                // [N] zeroed
  int*   pos      = meta + N;            // [N] zeroed
  int*   base     = meta + 2 * N;        // [N]
  int*   counter  = meta + 3 * N;        // [1] zeroed
  int2*  csr_pack = (int2*) carve(sizeof(int2) * (size_t)E);
  float* xl       = (float*)carve(sizeof(float) * (size_t)N * 128);
  float* xr       = (float*)carve(sizeof(float) * (size_t)N * 128);
  float* hA       = (float*)carve(sizeof(float) * (size_t)N * 128);
  float* hB       = (float*)carve(sizeof(float) * (size_t)N * 128);
  // prepacked bf16 hi/lo weights, MFMA B-fragment order
  short* ph1 = (short*)carve(sizeof(short) * 4096);
  short* pl1 = (short*)carve(sizeof(short) * 4096);
  short* ph2 = (short*)carve(sizeof(short) * 32768);
  short* pl2 = (short*)carve(sizeof(short) * 32768);
  short* ph3 = (short*)carve(sizeof(short) * 32768);
  short* pl3 = (short*)carve(sizeof(short) * 32768);
  short* ph4 = (short*)carve(sizeof(short) * 16384);
  short* pl4 = (short*)carve(sizeof(short) * 16384);

  hipMemsetAsync(deg,     0, sizeof(int) * (size_t)(2 * N), stream);
  hipMemsetAsync(counter, 0, sizeof(int), stream);

  int eb = (E + 255) / 256;
  int nb = (N + 255) / 256;
  deg_count_kernel  <<<eb, 256, 0, stream>>>(ei + E, deg, E);
  base_assign_kernel<<<nb, 256, 0, stream>>>(deg, base, counter, N);
  fill_kernel       <<<eb, 256, 0, stream>>>(ei, ea, base, pos, csr_pack, E);
  prep_w_kernel     <<<42, 256, 0, stream>>>(P[0],  P[2],  ph1, pl1,
                                             P[7],  P[9],  ph2, pl2,
                                             P[14], P[16], ph3, pl3,
                                             P[21], P[23], ph4, pl4);

  int gm    = (N + 63) / 64;  // 64-row MFMA tiles
  int agrid = 2048;           // agg: grid-stride, 8 waves/block

  // layer 1: din=15, H*C=128, ELU
  gemm_dual_mfma<128, 15><<<gm, 256, 0, stream>>>(x, ph1, pl1, P[1], P[3], xl, xr, N);
  agg_kernel<16><<<agrid, 512, 0, stream>>>(xl, xr, base, deg, csr_pack, P[4], P[5], P[6], hA,
                                            nullptr, nullptr, nullptr, N, 1);
  // layer 2: din=128, ELU
  gemm_dual_mfma<128, 128><<<gm, 256, 0, stream>>>(hA, ph2, pl2, P[8], P[10], xl, xr, N);
  agg_kernel<16><<<agrid, 512, 0, stream>>>(xl, xr, base, deg, csr_pack, P[11], P[12], P[13], hB,
                                            nullptr, nullptr, nullptr, N, 1);
  // layer 3: din=128, ELU
  gemm_dual_mfma<128, 128><<<gm, 256, 0, stream>>>(hB, ph3, pl3, P[15], P[17], xl, xr, N);
  agg_kernel<16><<<agrid, 512, 0, stream>>>(xl, xr, base, deg, csr_pack, P[18], P[19], P[20], hA,
                                            nullptr, nullptr, nullptr, N, 1);
  // layer 4: din=128, H*C=64, no ELU + fused final linear 64->1
  gemm_dual_mfma<64, 128><<<gm, 256, 0, stream>>>(hA, ph4, pl4, P[22], P[24], xl, xr, N);
  agg_kernel<8><<<agrid, 512, 0, stream>>>(xl, xr, base, deg, csr_pack, P[25], P[26], P[27], hB,
                                           Wlin, blin, (float*)d_out, N, 0);
}